// Round 6
// baseline (235.504 us; speedup 1.0000x reference)
//
#include <hip/hip_runtime.h>

#define FDIM 128
#define FCLS 40
#define EPB  2048      // edges per binning block
#define BSH  8         // bucket shift: 256 nodes per bucket
#define BKN  (1 << BSH)

typedef short s16x8 __attribute__((ext_vector_type(8)));   // 8 bf16 (4 VGPRs)
typedef float f32x4 __attribute__((ext_vector_type(4)));   // MFMA accumulator

// ---- bf16 helpers (bit-level, RNE) ----------------------------------------
__device__ __forceinline__ float bf2f(unsigned short u) {
    union { unsigned int i; float f; } v; v.i = ((unsigned int)u) << 16; return v.f;
}
__device__ __forceinline__ unsigned short f2bf(float f) {
    union { float f; unsigned int i; } v; v.f = f;
    unsigned int u = v.i + 0x7FFFu + ((v.i >> 16) & 1u);   // round-nearest-even
    return (unsigned short)(u >> 16);
}

// ---------------------------------------------------------------------------
// CSR build, bucketed (no global atomics):
// 1) bin_hist:        per-block LDS histogram of dst>>BSH -> hist[bin][blk]
// 2) bucket_scan:     exclusive scan of hist (1 block). hist[b*nblkA] then
//                     equals bucket b's base in BOTH binned[] and srcAdj[].
// 3) bin_scatter:     (src,dst) pairs -> binned[], grouped by bucket
// 4) node_hist_scan:  per-bucket LDS node histogram + in-LDS scan
//                     -> offsets[] + dinv[] directly (no global node scan)
// 5) csr_scatter:     per-bucket exact positions via LDS cursors -> srcAdj[]
// ---------------------------------------------------------------------------
__global__ __launch_bounds__(256) void bin_hist(const int* __restrict__ dst,
                                                int* __restrict__ hist,
                                                int E, int nblkA, int NB) {
    __shared__ int h[BKN];
    int t = threadIdx.x;
    for (int i = t; i < BKN; i += 256) h[i] = 0;
    __syncthreads();
    int base = blockIdx.x * EPB;
    int end = min(base + EPB, E);
    for (int i = base + t; i < end; i += 256) atomicAdd(&h[dst[i] >> BSH], 1);
    __syncthreads();
    for (int i = t; i < NB; i += 256) hist[i * nblkA + blockIdx.x] = h[i];
}

// single-block exclusive scan, 4096 elems/iter (16/thread)
__global__ __launch_bounds__(256) void bucket_scan(int* __restrict__ data, int n) {
    __shared__ int s[256];
    __shared__ int carryS;
    int t = threadIdx.x;
    if (t == 0) carryS = 0;
    __syncthreads();
    for (int base = 0; base < n; base += 4096) {
        int v[16]; int sum = 0;
        int idx = base + t * 16;
#pragma unroll
        for (int j = 0; j < 16; ++j) { v[j] = (idx + j < n) ? data[idx + j] : 0; sum += v[j]; }
        s[t] = sum;
        __syncthreads();
        for (int off = 1; off < 256; off <<= 1) {
            int x = (t >= off) ? s[t - off] : 0;
            __syncthreads();
            s[t] += x;
            __syncthreads();
        }
        int run = carryS + s[t] - sum;
#pragma unroll
        for (int j = 0; j < 16; ++j) {
            if (idx + j < n) data[idx + j] = run;
            run += v[j];
        }
        int tot = s[255];
        __syncthreads();
        if (t == 0) carryS += tot;
        __syncthreads();
    }
}

__global__ __launch_bounds__(256) void bin_scatter(const int* __restrict__ src,
                                                   const int* __restrict__ dst,
                                                   const int* __restrict__ histS,
                                                   int2* __restrict__ binned,
                                                   int E, int nblkA, int NB) {
    __shared__ int cur[BKN];
    int t = threadIdx.x;
    for (int i = t; i < NB; i += 256) cur[i] = histS[i * nblkA + blockIdx.x];
    __syncthreads();
    int base = blockIdx.x * EPB;
    int end = min(base + EPB, E);
    for (int i = base + t; i < end; i += 256) {
        int d = dst[i];
        int pos = atomicAdd(&cur[d >> BSH], 1);     // LDS atomic
        binned[pos] = make_int2(src[i], d);
    }
}

// per-bucket node histogram + in-LDS exclusive scan -> offsets, dinv
__global__ __launch_bounds__(256) void node_hist_scan(const int2* __restrict__ binned,
                                                      const int* __restrict__ histS,
                                                      int* __restrict__ offsets,
                                                      float* __restrict__ dinv,
                                                      int N, int E, int nblkA, int NB) {
    int b = blockIdx.x;
    int node0 = b << BSH;
    int t = threadIdx.x;
    __shared__ int c[BKN];
    c[t] = 0;
    __syncthreads();
    int lo = histS[b * nblkA];
    int hi = (b == NB - 1) ? E : histS[(b + 1) * nblkA];
    for (int i = lo + t; i < hi; i += 256) {
        int2 p = binned[i];
        atomicAdd(&c[p.y - node0], 1);              // LDS atomic
    }
    __syncthreads();
    int v = c[t];
    // inclusive Hillis-Steele scan over the bucket's 256 counts
    for (int off = 1; off < 256; off <<= 1) {
        int x = (t >= off) ? c[t - off] : 0;
        __syncthreads();
        c[t] += x;
        __syncthreads();
    }
    int excl = lo + c[t] - v;                       // bucket base + exclusive prefix
    int idx = node0 + t;
    if (idx < N) {
        offsets[idx] = excl;
        dinv[idx] = rsqrtf((float)v + 1.0f);
        if (idx == N - 1) offsets[N] = excl + v;    // == E
    }
}

__global__ __launch_bounds__(256) void csr_scatter(const int2* __restrict__ binned,
                                                   const int* __restrict__ offsets,
                                                   int* __restrict__ srcAdj, int N) {
    int b = blockIdx.x;
    int node0 = b << BSH;
    int node1 = min(node0 + BKN, N);
    __shared__ int cur[BKN];
    int t = threadIdx.x;
    if (node0 + t < node1) cur[t] = offsets[node0 + t];
    __syncthreads();
    int lo = offsets[node0];
    int hi = offsets[node1];
    for (int i = lo + t; i < hi; i += 256) {
        int2 p = binned[i];
        int pos = atomicAdd(&cur[p.y - node0], 1);   // LDS atomic
        srcAdj[pos] = p.x;                           // write stays in bucket's L2 region
    }
}

// ---------------------------------------------------------------------------
// prep: pack all three weights into MFMA B-fragment order, bf16 (1 dispatch).
// blocks 0-7: W1 (128 cols), 8-15: W2 (128), 16-18: Wc (40, zero-padded)
// ---------------------------------------------------------------------------
__global__ __launch_bounds__(256) void pack_all(const float* __restrict__ W1,
                                                const float* __restrict__ W2,
                                                const float* __restrict__ Wc,
                                                unsigned short* __restrict__ Wp1,
                                                unsigned short* __restrict__ Wp2,
                                                unsigned short* __restrict__ Wpc) {
    int blk = blockIdx.x;
    const float* W; unsigned short* Wp; int ncols, ct;
    if (blk < 8)       { W = W1; Wp = Wp1; ncols = FDIM; ct = blk; }
    else if (blk < 16) { W = W2; Wp = Wp2; ncols = FDIM; ct = blk - 8; }
    else               { W = Wc; Wp = Wpc; ncols = FCLS; ct = blk - 16; }
    int t = ct * 256 + threadIdx.x;
    int lane = t & 63, ks = (t >> 6) & 3;
    int n  = ct * 16 + (lane & 15);
    int kb = ks * 32 + (lane >> 4) * 8;
    unsigned short v[8];
#pragma unroll
    for (int j = 0; j < 8; ++j) {
        v[j] = (n < ncols) ? f2bf(W[(size_t)(kb + j) * ncols + n]) : (unsigned short)0;
    }
    ushort4* o = (ushort4*)(Wp + (size_t)t * 8);
    o[0] = ushort4{v[0], v[1], v[2], v[3]};
    o[1] = ushort4{v[4], v[5], v[6], v[7]};
}

// ---------------------------------------------------------------------------
// C[M,128](bf16) = A[M,128](f32, converted in-register) @ W(packed bf16)
// ---------------------------------------------------------------------------
__global__ __launch_bounds__(256) void gemm_mfma_f32A(const float* __restrict__ A,
                                                      const unsigned short* __restrict__ Wp,
                                                      unsigned short* __restrict__ C, int M) {
    int wave = threadIdx.x >> 6;
    int lane = threadIdx.x & 63;
    int row0 = (blockIdx.x * 4 + wave) * 16;
    if (row0 >= M) return;
    int m = lane & 15;
    int g = lane >> 4;

    const float4* Arow = (const float4*)(A + (size_t)(row0 + m) * FDIM);
    s16x8 a[4];
#pragma unroll
    for (int ks = 0; ks < 4; ++ks) {
        float4 lo = Arow[ks * 8 + g * 2];
        float4 hi = Arow[ks * 8 + g * 2 + 1];
        s16x8 av;
        av[0] = (short)f2bf(lo.x); av[1] = (short)f2bf(lo.y);
        av[2] = (short)f2bf(lo.z); av[3] = (short)f2bf(lo.w);
        av[4] = (short)f2bf(hi.x); av[5] = (short)f2bf(hi.y);
        av[6] = (short)f2bf(hi.z); av[7] = (short)f2bf(hi.w);
        a[ks] = av;
    }

    for (int ct = 0; ct < 8; ++ct) {
        f32x4 acc = {0.f, 0.f, 0.f, 0.f};
#pragma unroll
        for (int ks = 0; ks < 4; ++ks) {
            s16x8 b = *(const s16x8*)(Wp + ((size_t)((ct * 4 + ks) * 64 + lane)) * 8);
            acc = __builtin_amdgcn_mfma_f32_16x16x32_bf16(a[ks], b, acc, 0, 0, 0);
        }
        int n  = ct * 16 + m;
        int r0 = row0 + g * 4;
#pragma unroll
        for (int r = 0; r < 4; ++r)
            C[(size_t)(r0 + r) * FDIM + n] = f2bf(acc[r]);
    }
}

// bf16-A variant (layer 2)
__global__ __launch_bounds__(256) void gemm_mfma(const unsigned short* __restrict__ A,
                                                 const unsigned short* __restrict__ Wp,
                                                 unsigned short* __restrict__ C, int M) {
    int wave = threadIdx.x >> 6;
    int lane = threadIdx.x & 63;
    int row0 = (blockIdx.x * 4 + wave) * 16;
    if (row0 >= M) return;
    int m = lane & 15;
    int g = lane >> 4;

    const s16x8* Arow = (const s16x8*)(A + (size_t)(row0 + m) * FDIM);
    s16x8 a[4];
#pragma unroll
    for (int ks = 0; ks < 4; ++ks) a[ks] = Arow[ks * 4 + g];

    for (int ct = 0; ct < 8; ++ct) {
        f32x4 acc = {0.f, 0.f, 0.f, 0.f};
#pragma unroll
        for (int ks = 0; ks < 4; ++ks) {
            s16x8 b = *(const s16x8*)(Wp + ((size_t)((ct * 4 + ks) * 64 + lane)) * 8);
            acc = __builtin_amdgcn_mfma_f32_16x16x32_bf16(a[ks], b, acc, 0, 0, 0);
        }
        int n  = ct * 16 + m;
        int r0 = row0 + g * 4;
#pragma unroll
        for (int r = 0; r < 4; ++r)
            C[(size_t)(r0 + r) * FDIM + n] = f2bf(acc[r]);
    }
}

// ---------------------------------------------------------------------------
// out[M,40](f32) = A[M,128](bf16) @ Wc(packed, zero-padded) + bc
// ---------------------------------------------------------------------------
__global__ __launch_bounds__(256) void classifier_mfma(const unsigned short* __restrict__ A,
                                                       const unsigned short* __restrict__ Wp,
                                                       const float* __restrict__ bc,
                                                       float* __restrict__ out, int M) {
    int wave = threadIdx.x >> 6;
    int lane = threadIdx.x & 63;
    int row0 = (blockIdx.x * 4 + wave) * 16;
    if (row0 >= M) return;
    int m = lane & 15;
    int g = lane >> 4;

    const s16x8* Arow = (const s16x8*)(A + (size_t)(row0 + m) * FDIM);
    s16x8 a[4];
#pragma unroll
    for (int ks = 0; ks < 4; ++ks) a[ks] = Arow[ks * 4 + g];

    for (int ct = 0; ct < 3; ++ct) {
        f32x4 acc = {0.f, 0.f, 0.f, 0.f};
#pragma unroll
        for (int ks = 0; ks < 4; ++ks) {
            s16x8 b = *(const s16x8*)(Wp + ((size_t)((ct * 4 + ks) * 64 + lane)) * 8);
            acc = __builtin_amdgcn_mfma_f32_16x16x32_bf16(a[ks], b, acc, 0, 0, 0);
        }
        int n = ct * 16 + m;
        if (n < FCLS) {
            float bias = bc[n];
            int r0 = row0 + g * 4;
#pragma unroll
            for (int r = 0; r < 4; ++r)
                out[(size_t)(r0 + r) * FCLS + n] = acc[r] + bias;
        }
    }
}

// ---------------------------------------------------------------------------
// Fused aggregation (bf16 gather -> bf16 out), f32 accumulation.
// 16 lanes per node, 16B (s16x8) per lane -> one row = 16 lanes x 16B.
// 16 nodes per 256-thread block, 4 rows in flight per wave.
// ---------------------------------------------------------------------------
__global__ __launch_bounds__(256) void agg_fused(const unsigned short* __restrict__ H,
                                                 const float* __restrict__ dinv,
                                                 const float* __restrict__ bias,
                                                 const int* __restrict__ srcAdj,
                                                 const int* __restrict__ offsets,
                                                 unsigned short* __restrict__ OUT, int N) {
    int node = blockIdx.x * 16 + (threadIdx.x >> 4);
    if (node >= N) return;
    int lane = threadIdx.x & 15;

    const s16x8* H8 = (const s16x8*)H;             // row stride = 16 s16x8
    float di = dinv[node];
    float d2 = di * di;

    s16x8 h = H8[(size_t)node * 16 + lane];
    float acc[8];
#pragma unroll
    for (int j = 0; j < 8; ++j) acc[j] = bf2f((unsigned short)h[j]) * d2;

    int e   = offsets[node];
    int end = offsets[node + 1];
    for (; e + 4 <= end; e += 4) {
        int s0 = srcAdj[e + 0], s1 = srcAdj[e + 1];
        int s2 = srcAdj[e + 2], s3 = srcAdj[e + 3];
        float c0 = dinv[s0] * di, c1 = dinv[s1] * di;
        float c2 = dinv[s2] * di, c3 = dinv[s3] * di;
        s16x8 a0 = H8[(size_t)s0 * 16 + lane];
        s16x8 a1 = H8[(size_t)s1 * 16 + lane];
        s16x8 a2 = H8[(size_t)s2 * 16 + lane];
        s16x8 a3 = H8[(size_t)s3 * 16 + lane];
#pragma unroll
        for (int j = 0; j < 8; ++j) {
            acc[j] = fmaf(bf2f((unsigned short)a0[j]), c0, acc[j]);
            acc[j] = fmaf(bf2f((unsigned short)a1[j]), c1, acc[j]);
            acc[j] = fmaf(bf2f((unsigned short)a2[j]), c2, acc[j]);
            acc[j] = fmaf(bf2f((unsigned short)a3[j]), c3, acc[j]);
        }
    }
    for (; e < end; ++e) {
        int s0 = srcAdj[e];
        float c0 = dinv[s0] * di;
        s16x8 a0 = H8[(size_t)s0 * 16 + lane];
#pragma unroll
        for (int j = 0; j < 8; ++j)
            acc[j] = fmaf(bf2f((unsigned short)a0[j]), c0, acc[j]);
    }

    float4 b0 = ((const float4*)bias)[lane * 2];
    float4 b1 = ((const float4*)bias)[lane * 2 + 1];
    float bb[8] = {b0.x, b0.y, b0.z, b0.w, b1.x, b1.y, b1.z, b1.w};
    s16x8 o;
#pragma unroll
    for (int j = 0; j < 8; ++j)
        o[j] = (short)f2bf(fmaxf(acc[j] + bb[j], 0.0f));
    ((s16x8*)OUT)[(size_t)node * 16 + lane] = o;
}

// ---------------------------------------------------------------------------
extern "C" void kernel_launch(void* const* d_in, const int* in_sizes, int n_in,
                              void* d_out, int out_size, void* d_ws, size_t ws_size,
                              hipStream_t stream) {
    const float* x  = (const float*)d_in[0];
    const int*   ei = (const int*)d_in[1];
    const float* W1 = (const float*)d_in[2];
    const float* b1 = (const float*)d_in[3];
    const float* W2 = (const float*)d_in[4];
    const float* b2 = (const float*)d_in[5];
    const float* Wc = (const float*)d_in[6];
    const float* bc = (const float*)d_in[7];
    float* out = (float*)d_out;

    int N = in_sizes[0] / FDIM;
    int E = in_sizes[1] / 2;
    const int* src = ei;
    const int* dst = ei + E;

    int nblkA = (E + EPB - 1) / EPB;            // 391
    int NB    = (N + BKN - 1) >> BSH;           // 196
    int mfmaBlocks = (N / 16 + 3) / 4;          // 782
    int aggBlocks  = (N + 15) / 16;             // 3125

    // workspace layout:
    // binned[E int2] | srcAdj[E] | offsets[N+1] | hist[NB*nblkA] | dinv[N]
    // | Wp1 | Wp2 | Wpc | Hbuf bf16 | Abuf bf16
    int2* binned   = (int2*)d_ws;
    int*  srcAdj   = (int*)(binned + E);
    int*  offsets  = srcAdj + E;
    int*  hist     = offsets + (N + 1);
    float* dinv    = (float*)(hist + NB * nblkA);
    unsigned short* Wp1 = (unsigned short*)(dinv + N);
    unsigned short* Wp2 = Wp1 + 8 * 4 * 64 * 8;
    unsigned short* Wpc = Wp2 + 8 * 4 * 64 * 8;
    unsigned short* Hbuf = Wpc + 3 * 4 * 64 * 8;
    unsigned short* Abuf = Hbuf + (size_t)N * FDIM;

    // ---- CSR build (5 dispatches, no global atomics) ----
    bin_hist<<<nblkA, 256, 0, stream>>>(dst, hist, E, nblkA, NB);
    bucket_scan<<<1, 256, 0, stream>>>(hist, NB * nblkA);
    bin_scatter<<<nblkA, 256, 0, stream>>>(src, dst, hist, binned, E, nblkA, NB);
    node_hist_scan<<<NB, 256, 0, stream>>>(binned, hist, offsets, dinv, N, E, nblkA, NB);
    csr_scatter<<<NB, 256, 0, stream>>>(binned, offsets, srcAdj, N);

    // ---- weight packing (1 dispatch) ----
    pack_all<<<19, 256, 0, stream>>>(W1, W2, Wc, Wp1, Wp2, Wpc);

    // ---- layer 1 (x read as f32, converted in-register) ----
    gemm_mfma_f32A<<<mfmaBlocks, 256, 0, stream>>>(x, Wp1, Hbuf, N);
    agg_fused<<<aggBlocks, 256, 0, stream>>>(Hbuf, dinv, b1, srcAdj, offsets, Abuf, N);

    // ---- layer 2 ----
    gemm_mfma<<<mfmaBlocks, 256, 0, stream>>>(Abuf, Wp2, Hbuf, N);
    agg_fused<<<aggBlocks, 256, 0, stream>>>(Hbuf, dinv, b2, srcAdj, offsets, Abuf, N);

    // ---- classifier ----
    classifier_mfma<<<mfmaBlocks, 256, 0, stream>>>(Abuf, Wpc, bc, out, N);
}

// Round 7
// 158.421 us; speedup vs baseline: 1.4866x; 1.4866x over previous
//
#include <hip/hip_runtime.h>

#define FDIM 128
#define FCLS 40
#define EPB  2048      // edges per binning block
#define BSH  8         // bucket shift: 256 nodes per bucket
#define BKN  (1 << BSH)

typedef short s16x8 __attribute__((ext_vector_type(8)));   // 8 bf16 (4 VGPRs)
typedef float f32x4 __attribute__((ext_vector_type(4)));   // MFMA accumulator

// ---- bf16 helpers (bit-level, RNE) ----------------------------------------
__device__ __forceinline__ float bf2f(unsigned short u) {
    union { unsigned int i; float f; } v; v.i = ((unsigned int)u) << 16; return v.f;
}
__device__ __forceinline__ unsigned short f2bf(float f) {
    union { float f; unsigned int i; } v; v.f = f;
    unsigned int u = v.i + 0x7FFFu + ((v.i >> 16) & 1u);   // round-nearest-even
    return (unsigned short)(u >> 16);
}

// ---------------------------------------------------------------------------
// CSR build, bucketed (no global atomics):
// 1) bin_hist:        per-block LDS histogram of dst>>BSH -> hist[bin][blk]
// 2) hscan_*:         hierarchical exclusive scan of hist (3 parallel dispatches)
// 3) bin_scatter:     (src,dst) pairs -> binned[], grouped by bucket
// 4) node_hist_scan:  per-bucket LDS node histogram + in-LDS scan -> offsets,dinv
// 5) csr_scatter:     per-bucket exact positions via LDS cursors -> srcAdj[]
// ---------------------------------------------------------------------------
__global__ __launch_bounds__(256) void bin_hist(const int* __restrict__ dst,
                                                int* __restrict__ hist,
                                                int E, int nblkA, int NB) {
    __shared__ int h[BKN];
    int t = threadIdx.x;
    for (int i = t; i < BKN; i += 256) h[i] = 0;
    __syncthreads();
    int base = blockIdx.x * EPB;
    int end = min(base + EPB, E);
    for (int i = base + t; i < end; i += 256) atomicAdd(&h[dst[i] >> BSH], 1);
    __syncthreads();
    for (int i = t; i < NB; i += 256) hist[i * nblkA + blockIdx.x] = h[i];
}

// ---- hierarchical exclusive scan of hist[n] (in-place), 1024 elems/block ----
__global__ __launch_bounds__(256) void hscan_partial(const int* __restrict__ data,
                                                     int* __restrict__ bsums, int n) {
    __shared__ int s[256];
    int t = threadIdx.x;
    int base = blockIdx.x * 1024 + t * 4;
    int v = 0;
#pragma unroll
    for (int j = 0; j < 4; ++j) if (base + j < n) v += data[base + j];
    s[t] = v;
    __syncthreads();
    for (int off = 128; off > 0; off >>= 1) {
        if (t < off) s[t] += s[t + off];
        __syncthreads();
    }
    if (t == 0) bsums[blockIdx.x] = s[0];
}

__global__ __launch_bounds__(256) void hscan_block(int* __restrict__ bsums, int nb) {
    __shared__ int s[256];
    int t = threadIdx.x;
    s[t] = (t < nb) ? bsums[t] : 0;
    __syncthreads();
    for (int off = 1; off < 256; off <<= 1) {
        int x = 0;
        if (t >= off) x = s[t - off];
        __syncthreads();
        s[t] += x;
        __syncthreads();
    }
    if (t < nb) bsums[t] = (t > 0) ? s[t - 1] : 0;   // exclusive
}

__global__ __launch_bounds__(256) void hscan_final(int* __restrict__ data,
                                                   const int* __restrict__ bsums, int n) {
    __shared__ int s[256];
    int t = threadIdx.x;
    int idx = blockIdx.x * 1024 + t * 4;
    int v[4];
    int sum = 0;
#pragma unroll
    for (int j = 0; j < 4; ++j) {
        v[j] = (idx + j < n) ? data[idx + j] : 0;
        sum += v[j];
    }
    s[t] = sum;
    __syncthreads();
    for (int off = 1; off < 256; off <<= 1) {
        int x = 0;
        if (t >= off) x = s[t - off];
        __syncthreads();
        s[t] += x;
        __syncthreads();
    }
    int running = bsums[blockIdx.x] + s[t] - sum;     // exclusive prefix
#pragma unroll
    for (int j = 0; j < 4; ++j) {
        if (idx + j < n) data[idx + j] = running;
        running += v[j];
    }
}

__global__ __launch_bounds__(256) void bin_scatter(const int* __restrict__ src,
                                                   const int* __restrict__ dst,
                                                   const int* __restrict__ histS,
                                                   int2* __restrict__ binned,
                                                   int E, int nblkA, int NB) {
    __shared__ int cur[BKN];
    int t = threadIdx.x;
    for (int i = t; i < NB; i += 256) cur[i] = histS[i * nblkA + blockIdx.x];
    __syncthreads();
    int base = blockIdx.x * EPB;
    int end = min(base + EPB, E);
    for (int i = base + t; i < end; i += 256) {
        int d = dst[i];
        int pos = atomicAdd(&cur[d >> BSH], 1);     // LDS atomic
        binned[pos] = make_int2(src[i], d);
    }
}

// per-bucket node histogram + in-LDS exclusive scan -> offsets, dinv
__global__ __launch_bounds__(256) void node_hist_scan(const int2* __restrict__ binned,
                                                      const int* __restrict__ histS,
                                                      int* __restrict__ offsets,
                                                      float* __restrict__ dinv,
                                                      int N, int E, int nblkA, int NB) {
    int b = blockIdx.x;
    int node0 = b << BSH;
    int t = threadIdx.x;
    __shared__ int c[BKN];
    c[t] = 0;
    __syncthreads();
    int lo = histS[b * nblkA];
    int hi = (b == NB - 1) ? E : histS[(b + 1) * nblkA];
    for (int i = lo + t; i < hi; i += 256) {
        int2 p = binned[i];
        atomicAdd(&c[p.y - node0], 1);              // LDS atomic
    }
    __syncthreads();
    int v = c[t];
    // inclusive Hillis-Steele scan over the bucket's 256 counts
    for (int off = 1; off < 256; off <<= 1) {
        int x = (t >= off) ? c[t - off] : 0;
        __syncthreads();
        c[t] += x;
        __syncthreads();
    }
    int excl = lo + c[t] - v;                       // bucket base + exclusive prefix
    int idx = node0 + t;
    if (idx < N) {
        offsets[idx] = excl;
        dinv[idx] = rsqrtf((float)v + 1.0f);
        if (idx == N - 1) offsets[N] = excl + v;    // == E
    }
}

__global__ __launch_bounds__(256) void csr_scatter(const int2* __restrict__ binned,
                                                   const int* __restrict__ offsets,
                                                   int* __restrict__ srcAdj, int N) {
    int b = blockIdx.x;
    int node0 = b << BSH;
    int node1 = min(node0 + BKN, N);
    __shared__ int cur[BKN];
    int t = threadIdx.x;
    if (node0 + t < node1) cur[t] = offsets[node0 + t];
    __syncthreads();
    int lo = offsets[node0];
    int hi = offsets[node1];
    for (int i = lo + t; i < hi; i += 256) {
        int2 p = binned[i];
        int pos = atomicAdd(&cur[p.y - node0], 1);   // LDS atomic
        srcAdj[pos] = p.x;                           // write stays in bucket's L2 region
    }
}

// ---------------------------------------------------------------------------
// prep: pack all three weights into MFMA B-fragment order, bf16 (1 dispatch).
// blocks 0-7: W1 (128 cols), 8-15: W2 (128), 16-18: Wc (40, zero-padded)
// ---------------------------------------------------------------------------
__global__ __launch_bounds__(256) void pack_all(const float* __restrict__ W1,
                                                const float* __restrict__ W2,
                                                const float* __restrict__ Wc,
                                                unsigned short* __restrict__ Wp1,
                                                unsigned short* __restrict__ Wp2,
                                                unsigned short* __restrict__ Wpc) {
    int blk = blockIdx.x;
    const float* W; unsigned short* Wp; int ncols, ct;
    if (blk < 8)       { W = W1; Wp = Wp1; ncols = FDIM; ct = blk; }
    else if (blk < 16) { W = W2; Wp = Wp2; ncols = FDIM; ct = blk - 8; }
    else               { W = Wc; Wp = Wpc; ncols = FCLS; ct = blk - 16; }
    int t = ct * 256 + threadIdx.x;
    int lane = t & 63, ks = (t >> 6) & 3;
    int n  = ct * 16 + (lane & 15);
    int kb = ks * 32 + (lane >> 4) * 8;
    unsigned short v[8];
#pragma unroll
    for (int j = 0; j < 8; ++j) {
        v[j] = (n < ncols) ? f2bf(W[(size_t)(kb + j) * ncols + n]) : (unsigned short)0;
    }
    ushort4* o = (ushort4*)(Wp + (size_t)t * 8);
    o[0] = ushort4{v[0], v[1], v[2], v[3]};
    o[1] = ushort4{v[4], v[5], v[6], v[7]};
}

// ---------------------------------------------------------------------------
// C[M,128](bf16) = A[M,128](f32, converted in-register) @ W(packed bf16)
// ---------------------------------------------------------------------------
__global__ __launch_bounds__(256) void gemm_mfma_f32A(const float* __restrict__ A,
                                                      const unsigned short* __restrict__ Wp,
                                                      unsigned short* __restrict__ C, int M) {
    int wave = threadIdx.x >> 6;
    int lane = threadIdx.x & 63;
    int row0 = (blockIdx.x * 4 + wave) * 16;
    if (row0 >= M) return;
    int m = lane & 15;
    int g = lane >> 4;

    const float4* Arow = (const float4*)(A + (size_t)(row0 + m) * FDIM);
    s16x8 a[4];
#pragma unroll
    for (int ks = 0; ks < 4; ++ks) {
        float4 lo = Arow[ks * 8 + g * 2];
        float4 hi = Arow[ks * 8 + g * 2 + 1];
        s16x8 av;
        av[0] = (short)f2bf(lo.x); av[1] = (short)f2bf(lo.y);
        av[2] = (short)f2bf(lo.z); av[3] = (short)f2bf(lo.w);
        av[4] = (short)f2bf(hi.x); av[5] = (short)f2bf(hi.y);
        av[6] = (short)f2bf(hi.z); av[7] = (short)f2bf(hi.w);
        a[ks] = av;
    }

    for (int ct = 0; ct < 8; ++ct) {
        f32x4 acc = {0.f, 0.f, 0.f, 0.f};
#pragma unroll
        for (int ks = 0; ks < 4; ++ks) {
            s16x8 b = *(const s16x8*)(Wp + ((size_t)((ct * 4 + ks) * 64 + lane)) * 8);
            acc = __builtin_amdgcn_mfma_f32_16x16x32_bf16(a[ks], b, acc, 0, 0, 0);
        }
        int n  = ct * 16 + m;
        int r0 = row0 + g * 4;
#pragma unroll
        for (int r = 0; r < 4; ++r)
            C[(size_t)(r0 + r) * FDIM + n] = f2bf(acc[r]);
    }
}

// bf16-A variant (layer 2)
__global__ __launch_bounds__(256) void gemm_mfma(const unsigned short* __restrict__ A,
                                                 const unsigned short* __restrict__ Wp,
                                                 unsigned short* __restrict__ C, int M) {
    int wave = threadIdx.x >> 6;
    int lane = threadIdx.x & 63;
    int row0 = (blockIdx.x * 4 + wave) * 16;
    if (row0 >= M) return;
    int m = lane & 15;
    int g = lane >> 4;

    const s16x8* Arow = (const s16x8*)(A + (size_t)(row0 + m) * FDIM);
    s16x8 a[4];
#pragma unroll
    for (int ks = 0; ks < 4; ++ks) a[ks] = Arow[ks * 4 + g];

    for (int ct = 0; ct < 8; ++ct) {
        f32x4 acc = {0.f, 0.f, 0.f, 0.f};
#pragma unroll
        for (int ks = 0; ks < 4; ++ks) {
            s16x8 b = *(const s16x8*)(Wp + ((size_t)((ct * 4 + ks) * 64 + lane)) * 8);
            acc = __builtin_amdgcn_mfma_f32_16x16x32_bf16(a[ks], b, acc, 0, 0, 0);
        }
        int n  = ct * 16 + m;
        int r0 = row0 + g * 4;
#pragma unroll
        for (int r = 0; r < 4; ++r)
            C[(size_t)(r0 + r) * FDIM + n] = f2bf(acc[r]);
    }
}

// ---------------------------------------------------------------------------
// out[M,40](f32) = A[M,128](bf16) @ Wc(packed, zero-padded) + bc
// ---------------------------------------------------------------------------
__global__ __launch_bounds__(256) void classifier_mfma(const unsigned short* __restrict__ A,
                                                       const unsigned short* __restrict__ Wp,
                                                       const float* __restrict__ bc,
                                                       float* __restrict__ out, int M) {
    int wave = threadIdx.x >> 6;
    int lane = threadIdx.x & 63;
    int row0 = (blockIdx.x * 4 + wave) * 16;
    if (row0 >= M) return;
    int m = lane & 15;
    int g = lane >> 4;

    const s16x8* Arow = (const s16x8*)(A + (size_t)(row0 + m) * FDIM);
    s16x8 a[4];
#pragma unroll
    for (int ks = 0; ks < 4; ++ks) a[ks] = Arow[ks * 4 + g];

    for (int ct = 0; ct < 3; ++ct) {
        f32x4 acc = {0.f, 0.f, 0.f, 0.f};
#pragma unroll
        for (int ks = 0; ks < 4; ++ks) {
            s16x8 b = *(const s16x8*)(Wp + ((size_t)((ct * 4 + ks) * 64 + lane)) * 8);
            acc = __builtin_amdgcn_mfma_f32_16x16x32_bf16(a[ks], b, acc, 0, 0, 0);
        }
        int n = ct * 16 + m;
        if (n < FCLS) {
            float bias = bc[n];
            int r0 = row0 + g * 4;
#pragma unroll
            for (int r = 0; r < 4; ++r)
                out[(size_t)(r0 + r) * FCLS + n] = acc[r] + bias;
        }
    }
}

// ---------------------------------------------------------------------------
// Fused aggregation (bf16 gather -> bf16 out), f32 accumulation.
// 16 lanes per node, 16B (s16x8) per lane; 16 nodes per 256-thread block.
// ---------------------------------------------------------------------------
__global__ __launch_bounds__(256) void agg_fused(const unsigned short* __restrict__ H,
                                                 const float* __restrict__ dinv,
                                                 const float* __restrict__ bias,
                                                 const int* __restrict__ srcAdj,
                                                 const int* __restrict__ offsets,
                                                 unsigned short* __restrict__ OUT, int N) {
    int node = blockIdx.x * 16 + (threadIdx.x >> 4);
    if (node >= N) return;
    int lane = threadIdx.x & 15;

    const s16x8* H8 = (const s16x8*)H;             // row stride = 16 s16x8
    float di = dinv[node];
    float d2 = di * di;

    s16x8 h = H8[(size_t)node * 16 + lane];
    float acc[8];
#pragma unroll
    for (int j = 0; j < 8; ++j) acc[j] = bf2f((unsigned short)h[j]) * d2;

    int e   = offsets[node];
    int end = offsets[node + 1];
    for (; e + 4 <= end; e += 4) {
        int s0 = srcAdj[e + 0], s1 = srcAdj[e + 1];
        int s2 = srcAdj[e + 2], s3 = srcAdj[e + 3];
        float c0 = dinv[s0] * di, c1 = dinv[s1] * di;
        float c2 = dinv[s2] * di, c3 = dinv[s3] * di;
        s16x8 a0 = H8[(size_t)s0 * 16 + lane];
        s16x8 a1 = H8[(size_t)s1 * 16 + lane];
        s16x8 a2 = H8[(size_t)s2 * 16 + lane];
        s16x8 a3 = H8[(size_t)s3 * 16 + lane];
#pragma unroll
        for (int j = 0; j < 8; ++j) {
            acc[j] = fmaf(bf2f((unsigned short)a0[j]), c0, acc[j]);
            acc[j] = fmaf(bf2f((unsigned short)a1[j]), c1, acc[j]);
            acc[j] = fmaf(bf2f((unsigned short)a2[j]), c2, acc[j]);
            acc[j] = fmaf(bf2f((unsigned short)a3[j]), c3, acc[j]);
        }
    }
    for (; e < end; ++e) {
        int s0 = srcAdj[e];
        float c0 = dinv[s0] * di;
        s16x8 a0 = H8[(size_t)s0 * 16 + lane];
#pragma unroll
        for (int j = 0; j < 8; ++j)
            acc[j] = fmaf(bf2f((unsigned short)a0[j]), c0, acc[j]);
    }

    float4 b0 = ((const float4*)bias)[lane * 2];
    float4 b1 = ((const float4*)bias)[lane * 2 + 1];
    float bb[8] = {b0.x, b0.y, b0.z, b0.w, b1.x, b1.y, b1.z, b1.w};
    s16x8 o;
#pragma unroll
    for (int j = 0; j < 8; ++j)
        o[j] = (short)f2bf(fmaxf(acc[j] + bb[j], 0.0f));
    ((s16x8*)OUT)[(size_t)node * 16 + lane] = o;
}

// ---------------------------------------------------------------------------
extern "C" void kernel_launch(void* const* d_in, const int* in_sizes, int n_in,
                              void* d_out, int out_size, void* d_ws, size_t ws_size,
                              hipStream_t stream) {
    const float* x  = (const float*)d_in[0];
    const int*   ei = (const int*)d_in[1];
    const float* W1 = (const float*)d_in[2];
    const float* b1 = (const float*)d_in[3];
    const float* W2 = (const float*)d_in[4];
    const float* b2 = (const float*)d_in[5];
    const float* Wc = (const float*)d_in[6];
    const float* bc = (const float*)d_in[7];
    float* out = (float*)d_out;

    int N = in_sizes[0] / FDIM;
    int E = in_sizes[1] / 2;
    const int* src = ei;
    const int* dst = ei + E;

    int nblkA = (E + EPB - 1) / EPB;            // 391
    int NB    = (N + BKN - 1) >> BSH;           // 196
    int mfmaBlocks = (N / 16 + 3) / 4;          // 782
    int aggBlocks  = (N + 15) / 16;             // 3125
    int histN = NB * nblkA;                     // 76636
    int hscanBlocks = (histN + 1023) / 1024;    // 75

    // workspace layout:
    // binned[E int2] | srcAdj[E] | offsets[N+1] | hist[NB*nblkA] | bsums[256]
    // | dinv[N] | Wp1 | Wp2 | Wpc | Hbuf bf16 | Abuf bf16
    int2* binned   = (int2*)d_ws;
    int*  srcAdj   = (int*)(binned + E);
    int*  offsets  = srcAdj + E;
    int*  hist     = offsets + (N + 1);
    int*  bsums    = hist + histN;
    float* dinv    = (float*)(bsums + 256);
    unsigned short* Wp1 = (unsigned short*)(dinv + N);
    unsigned short* Wp2 = Wp1 + 8 * 4 * 64 * 8;
    unsigned short* Wpc = Wp2 + 8 * 4 * 64 * 8;
    unsigned short* Hbuf = Wpc + 3 * 4 * 64 * 8;
    unsigned short* Abuf = Hbuf + (size_t)N * FDIM;

    // ---- CSR build (7 dispatches, no global atomics, all parallel) ----
    bin_hist<<<nblkA, 256, 0, stream>>>(dst, hist, E, nblkA, NB);
    hscan_partial<<<hscanBlocks, 256, 0, stream>>>(hist, bsums, histN);
    hscan_block<<<1, 256, 0, stream>>>(bsums, hscanBlocks);
    hscan_final<<<hscanBlocks, 256, 0, stream>>>(hist, bsums, histN);
    bin_scatter<<<nblkA, 256, 0, stream>>>(src, dst, hist, binned, E, nblkA, NB);
    node_hist_scan<<<NB, 256, 0, stream>>>(binned, hist, offsets, dinv, N, E, nblkA, NB);
    csr_scatter<<<NB, 256, 0, stream>>>(binned, offsets, srcAdj, N);

    // ---- weight packing (1 dispatch) ----
    pack_all<<<19, 256, 0, stream>>>(W1, W2, Wc, Wp1, Wp2, Wpc);

    // ---- layer 1 (x read as f32, converted in-register) ----
    gemm_mfma_f32A<<<mfmaBlocks, 256, 0, stream>>>(x, Wp1, Hbuf, N);
    agg_fused<<<aggBlocks, 256, 0, stream>>>(Hbuf, dinv, b1, srcAdj, offsets, Abuf, N);

    // ---- layer 2 ----
    gemm_mfma<<<mfmaBlocks, 256, 0, stream>>>(Abuf, Wp2, Hbuf, N);
    agg_fused<<<aggBlocks, 256, 0, stream>>>(Hbuf, dinv, b2, srcAdj, offsets, Abuf, N);

    // ---- classifier ----
    classifier_mfma<<<mfmaBlocks, 256, 0, stream>>>(Abuf, Wpc, bc, out, N);
}